// Round 19
// baseline (380.916 us; speedup 1.0000x reference)
//
#include <hip/hip_runtime.h>

#define HH 128
#define WW 256
#define DEPTH 4          // ring slots per wave (S) and shared (F)
#define AHEAD 3          // channel-pairs in flight
#define NCP 32           // 64 channels -> 32 channel-pairs
#define PLANE 32768      // H*W dwords per plane
#define PACKED_DWORDS 4194304ull   // packed S: 4 b * 32 cp * 32768
#define ZOFF PACKED_DWORDS         // zero region: 1024 dwords after packed S

typedef unsigned int u32;
typedef _Float16 f16;
typedef f16 f16x2 __attribute__((ext_vector_type(2)));
typedef u32 u32x4 __attribute__((ext_vector_type(4)));

union U32H2 { u32 u; f16x2 h; };

// async global->LDS, 16B/lane: global src per-lane, LDS dest uniform base + lane*16.
__device__ __forceinline__ void gload_lds16(const u32* g, u32* l) {
  __builtin_amdgcn_global_load_lds(
      (const __attribute__((address_space(1))) u32*)g,
      (__attribute__((address_space(3))) u32*)l, 16, 0, 0);
}

// Per-role counted drains: wv<8 issues 1 vmem/pair, wv8 issues 3/pair.
__device__ __forceinline__ void waitS(int rem) {   // rem compile-time after unroll
  if      (rem >= 2) asm volatile("s_waitcnt vmcnt(2)" ::: "memory");
  else if (rem == 1) asm volatile("s_waitcnt vmcnt(1)" ::: "memory");
  else               asm volatile("s_waitcnt vmcnt(0)" ::: "memory");
}
__device__ __forceinline__ void waitSF(int rem) {
  if      (rem >= 2) asm volatile("s_waitcnt vmcnt(6)" ::: "memory");
  else if (rem == 1) asm volatile("s_waitcnt vmcnt(3)" ::: "memory");
  else               asm volatile("s_waitcnt vmcnt(0)" ::: "memory");
}

// ---- pack S + zero the OOB region (block 0) ----
__global__ __launch_bounds__(256) void pack_s(
    const float* __restrict__ src, u32* __restrict__ dst, u32* __restrict__ zws)
{
  if (blockIdx.x == 0)                      // 256 thr x 16B = 4 KB zero region
    ((float4*)zws)[threadIdx.x] = make_float4(0.f, 0.f, 0.f, 0.f);
  const int di  = blockIdx.x * 1024 + threadIdx.x * 4;
  const int p   = di & (PLANE - 1);
  const int cpb = di >> 15;
  const int bI  = cpb >> 5, cp = cpb & 31;
  const size_t s0 = ((size_t)(bI * 64 + cp * 2)) * PLANE + p;
  const float4 x = *(const float4*)(src + s0);
  const float4 y = *(const float4*)(src + s0 + PLANE);
  U32H2 h0, h1, h2, h3;
  h0.h = f16x2{(f16)x.x, (f16)y.x};
  h1.h = f16x2{(f16)x.y, (f16)y.y};
  h2.h = f16x2{(f16)x.z, (f16)y.z};
  h3.h = f16x2{(f16)x.w, (f16)y.w};
  *(u32x4*)(dst + di) = (u32x4){h0.u, h1.u, h2.u, h3.u};
}

// ---- correlation: block=(b,h), 9 dy-waves. S rows per-wave via LDS ring;
// F rows (fp32) staged to SHARED LDS ring by wave 8 only -> 11 vmem issues
// per block-cp instead of 27. Raw s_barrier (no compiler vmcnt(0) drain) +
// per-role counted waits keep the pipeline in flight across barriers.
__global__ __launch_bounds__(576, 5) void corr_f16(
    const u32* __restrict__ ps, const float* __restrict__ first,
    const u32* __restrict__ zws, float* __restrict__ out)
{
  __shared__ u32 sS[9][DEPTH * 264];        // 38016 B
  __shared__ u32 sF[DEPTH][2][256];         // 8192 B (fp32 rows c, c+1)

  const int tid  = threadIdx.x;
  const int lane = tid & 63;
  const int dy   = __builtin_amdgcn_readfirstlane(tid >> 6);  // 0..8, wave-uniform
  const int bid  = blockIdx.x;
  const int xcd  = bid & 7;                 // contiguous 16-row h band per XCD
  const int idx  = bid >> 3;                // 0..63
  const int h    = xcd * 16 + (idx & 15);
  const int b    = idx >> 4;                // 0..3
  const int l4   = lane * 4;

  float* obase = out + (((size_t)(b * 81 + dy * 9)) * HH + h) * WW + l4;
  const int gh = h + dy - 4;
  const bool ok = (0 <= gh && gh < HH);     // OOB: stay in loop (barriers!),
                                            // read zeros -> acc stays 0 (correct).
  u32* S = &sS[dy][0];                      // 4 slots x [4 pad | 256 | 4 pad]
  if (lane < DEPTH * 8) {                   // zero side-pads once (wave-private)
    const int slot = lane >> 3, pd = lane & 7;
    S[slot * 264 + (pd < 4 ? pd : 256 + pd)] = 0;
  }

  const u32* sg = (ok ? ps + (size_t)(b * NCP) * PLANE + (size_t)gh * WW : zws) + l4;
  const size_t sst = ok ? PLANE : 0;        // OOB: stride 0, stay in 4 KB zeros
  const float* fg = first + (size_t)(b * 64) * PLANE + (size_t)h * WW + l4;

  auto pair = [&](int cp) {                 // wv<8: 1 vmem; wv8: 3 vmem
    const int slot = cp % DEPTH;
    gload_lds16(sg, S + slot * 264 + 4);
    sg += sst;
    if (dy == 8) {                          // wave-uniform branch
      gload_lds16((const u32*)(fg + (size_t)(2 * cp) * PLANE),     &sF[slot][0][0]);
      gload_lds16((const u32*)(fg + (size_t)(2 * cp + 1) * PLANE), &sF[slot][1][0]);
    }
  };

#pragma unroll
  for (int cp = 0; cp < AHEAD; ++cp) pair(cp);

  float acc[36];
#pragma unroll
  for (int k = 0; k < 36; ++k) acc[k] = 0.f;

#pragma unroll
  for (int cp = 0; cp < NCP; ++cp) {
    const int rem = NCP - 1 - cp;
    if (dy == 8) waitSF(rem); else waitS(rem);   // own pair-cp ops drained
    asm volatile("s_barrier" ::: "memory");      // RAW barrier: no vmcnt(0) drain
    __builtin_amdgcn_sched_barrier(0);           // no ds_read hoists above it

    const int slot = cp % DEPTH;
    const u32x4 s0 = *(const u32x4*)(S + slot * 264 + l4);       // w-4..w-1
    const u32x4 s1 = *(const u32x4*)(S + slot * 264 + l4 + 4);   // w..w+3
    const u32x4 s2 = *(const u32x4*)(S + slot * 264 + l4 + 8);   // w+4..w+7
    const float4 fA = *(const float4*)&sF[slot][0][l4];          // F row c
    const float4 fB = *(const float4*)&sF[slot][1][l4];          // F row c+1
    if (cp + AHEAD < NCP) pair(cp + AHEAD);
    // Slot reuse safe: readers of slot (cp-1)%4 completed at cp-1 (dot2
    // data-use forces lgkm) before barrier(cp) ordered this cp's writes.

    U32H2 f_[4];                            // RNE fp32->f16 (matches pack_s)
    f_[0].h = f16x2{(f16)fA.x, (f16)fB.x};
    f_[1].h = f16x2{(f16)fA.y, (f16)fB.y};
    f_[2].h = f16x2{(f16)fA.z, (f16)fB.z};
    f_[3].h = f16x2{(f16)fA.w, (f16)fB.w};

    U32H2 s_[12];
#pragma unroll
    for (int j = 0; j < 4; ++j) { s_[j].u = s0[j]; s_[j + 4].u = s1[j]; s_[j + 8].u = s2[j]; }
#pragma unroll
    for (int dx = 0; dx < 9; ++dx)
#pragma unroll
      for (int i = 0; i < 4; ++i)
        acc[dx * 4 + i] = __builtin_amdgcn_fdot2(f_[i].h, s_[i + dx].h,
                                                 acc[dx * 4 + i], false);
  }

  const float sc = 1.0f / 64.0f;
#pragma unroll
  for (int dx = 0; dx < 9; ++dx) {
    float4 v = make_float4(acc[dx * 4 + 0] * sc, acc[dx * 4 + 1] * sc,
                           acc[dx * 4 + 2] * sc, acc[dx * 4 + 3] * sc);
    *(float4*)(obase + (size_t)dx * PLANE) = v;
  }
}

// ---- fallback (proven-correct fp32 path) if ws is too small ----
__global__ __launch_bounds__(576) void corr_fp32_fb(
    const float* __restrict__ first, const float* __restrict__ second,
    float* __restrict__ out)
{
  const int tid  = threadIdx.x;
  const int lane = tid & 63;
  const int wv   = tid >> 6;
  const int bid  = blockIdx.x;
  const int idx  = bid >> 3;
  const int h    = (bid & 7) * 16 + (idx & 15);
  const int b    = idx >> 4;
  const int l4   = lane * 4;
  const size_t plane = (size_t)HH * WW;
  float* obase = out + (((size_t)b * 81 + (size_t)wv * 9) * HH + h) * WW + l4;
  const int gh = h + wv - 4;
  if (gh < 0 || gh >= HH) {
    const float4 z = make_float4(0.f, 0.f, 0.f, 0.f);
#pragma unroll
    for (int dx = 0; dx < 9; ++dx) *(float4*)(obase + (size_t)dx * plane) = z;
    return;
  }
  const float* frow = first  + ((size_t)b * 64 * HH + h ) * WW;
  const float* srow = second + ((size_t)b * 64 * HH + gh) * WW;
  const bool zL = (lane == 0), zR = (lane == 63);
  const int offL = zL ? l4 : l4 - 4;
  const int offR = zR ? l4 : l4 + 4;
  float acc[9][4];
#pragma unroll
  for (int dx = 0; dx < 9; ++dx)
#pragma unroll
    for (int i = 0; i < 4; ++i) acc[dx][i] = 0.f;
#pragma unroll 2
  for (int c = 0; c < 64; ++c) {
    const size_t cp = (size_t)c * plane;
    float4 f  = *(const float4*)(frow + cp + l4);
    float4 aL = *(const float4*)(srow + cp + offL);
    float4 aM = *(const float4*)(srow + cp + l4);
    float4 aR = *(const float4*)(srow + cp + offR);
    if (zL) { aL.x = aL.y = aL.z = aL.w = 0.f; }
    if (zR) { aR.x = aR.y = aR.z = aR.w = 0.f; }
    const float fv[4]  = {f.x, f.y, f.z, f.w};
    const float sv[12] = {aL.x, aL.y, aL.z, aL.w, aM.x, aM.y, aM.z, aM.w,
                          aR.x, aR.y, aR.z, aR.w};
#pragma unroll
    for (int dx = 0; dx < 9; ++dx)
#pragma unroll
      for (int i = 0; i < 4; ++i)
        acc[dx][i] = fmaf(fv[i], sv[i + dx], acc[dx][i]);
  }
  const float sc = 1.0f / 64.0f;
#pragma unroll
  for (int dx = 0; dx < 9; ++dx) {
    float4 v = make_float4(acc[dx][0] * sc, acc[dx][1] * sc,
                           acc[dx][2] * sc, acc[dx][3] * sc);
    *(float4*)(obase + (size_t)dx * plane) = v;
  }
}

extern "C" void kernel_launch(void* const* d_in, const int* in_sizes, int n_in,
                              void* d_out, int out_size, void* d_ws, size_t ws_size,
                              hipStream_t stream) {
  const float* first  = (const float*)d_in[0];
  const float* second = (const float*)d_in[1];
  float* out = (float*)d_out;
  (void)in_sizes; (void)n_in; (void)out_size;

  if (ws_size >= (PACKED_DWORDS + 1024) * 4ull) {
    u32* psecond = (u32*)d_ws;
    u32* zws = psecond + ZOFF;
    pack_s  <<<dim3(4096), dim3(256), 0, stream>>>(second, psecond, zws);
    corr_f16<<<dim3(512),  dim3(576), 0, stream>>>(psecond, first, zws, out);
  } else {
    corr_fp32_fb<<<dim3(512), dim3(576), 0, stream>>>(first, second, out);
  }
}

// Round 20
// 40.798 us; speedup vs baseline: 9.3367x; 9.3367x over previous
//
#include <hip/hip_runtime.h>

#define HH 128
#define WW 256
#define DEPTH 4          // LDS/F ring slots per wave
#define AHEAD 3          // channel-pairs in flight; 2 vmem per pair
#define NCP 32           // 64 channels -> 32 channel-pairs
#define PLANE 32768      // H*W dwords per plane
#define PACKED_DWORDS 4194304ull   // per-array packed: 4 b * 32 cp * 32768

typedef unsigned int u32;
typedef _Float16 f16;
typedef f16 f16x2 __attribute__((ext_vector_type(2)));
typedef u32 u32x4 __attribute__((ext_vector_type(4)));

union U32H2 { u32 u; f16x2 h; };

// async global->LDS, 16B/lane: global src per-lane, LDS dest uniform base + lane*16.
__device__ __forceinline__ void gload_lds16(const u32* g, u32* l) {
  __builtin_amdgcn_global_load_lds(
      (const __attribute__((address_space(1))) u32*)g,
      (__attribute__((address_space(3))) u32*)l, 16, 0, 0);
}

// Two-stage drains for 2-op pairs issued [S, F]:
// waitA completes S_cp (LDS ready for ds_read); waitB completes F_cp (regs),
// called AFTER pair(cp+3) issue. Ladders trace-verified.
__device__ __forceinline__ void waitA(int rem) {   // rem compile-time after unroll
  if      (rem >= 2) asm volatile("s_waitcnt vmcnt(5)" ::: "memory");
  else if (rem == 1) asm volatile("s_waitcnt vmcnt(3)" ::: "memory");
  else               asm volatile("s_waitcnt vmcnt(1)" ::: "memory");
}
__device__ __forceinline__ void waitB(int rem) {
  if      (rem >= 3) asm volatile("s_waitcnt vmcnt(6)" ::: "memory");
  else if (rem == 2) asm volatile("s_waitcnt vmcnt(4)" ::: "memory");
  else if (rem == 1) asm volatile("s_waitcnt vmcnt(2)" ::: "memory");
  else               asm volatile("s_waitcnt vmcnt(0)" ::: "memory");
}

// ---- pack BOTH arrays: fp32 [b][c][h][w] -> dword=half2(c,c+1) ----
__global__ __launch_bounds__(256) void pack_kernel(
    const float* __restrict__ a, const float* __restrict__ b,
    u32* __restrict__ pa, u32* __restrict__ pb)
{
  int bid = blockIdx.x;
  const float* src = a; u32* dst = pa;
  if (bid >= 4096) { src = b; dst = pb; bid -= 4096; }
  const int di  = bid * 1024 + threadIdx.x * 4;
  const int p   = di & (PLANE - 1);
  const int cpb = di >> 15;
  const int bI  = cpb >> 5, cp = cpb & 31;
  const size_t s0 = ((size_t)(bI * 64 + cp * 2)) * PLANE + p;
  const float4 x = *(const float4*)(src + s0);
  const float4 y = *(const float4*)(src + s0 + PLANE);
  U32H2 h0, h1, h2, h3;
  h0.h = f16x2{(f16)x.x, (f16)y.x};
  h1.h = f16x2{(f16)x.y, (f16)y.y};
  h2.h = f16x2{(f16)x.z, (f16)y.z};
  h3.h = f16x2{(f16)x.w, (f16)y.w};
  *(u32x4*)(dst + di) = (u32x4){h0.u, h1.u, h2.u, h3.u};
}

// ---- correlation: block=(b,h), 9 dy-waves (proven template). Both inputs
// packed: pair = 2 vmem (S-gload + packed-F dwordx4) -> 18 issues/block-cp.
// Two-stage vmcnt so ds_reads overlap the F tail. No barriers.
__global__ __launch_bounds__(576, 5) void corr_f16(
    const u32* __restrict__ ps, const u32* __restrict__ pf,
    float* __restrict__ out)
{
  __shared__ u32 lds[9][DEPTH * 264];              // 38016 B/block

  const int tid  = threadIdx.x;
  const int lane = tid & 63;
  const int dy   = __builtin_amdgcn_readfirstlane(tid >> 6);  // 0..8, wave-uniform
  const int bid  = blockIdx.x;
  const int xcd  = bid & 7;                 // contiguous 16-row h band per XCD
  const int idx  = bid >> 3;                // 0..63
  const int h    = xcd * 16 + (idx & 15);
  const int b    = idx >> 4;                // 0..3
  const int l4   = lane * 4;

  float* obase = out + (((size_t)(b * 81 + dy * 9)) * HH + h) * WW + l4;
  const int gh = h + dy - 4;
  if (gh < 0 || gh >= HH) {                 // whole row OOB -> zeros, exit
    const float4 z = make_float4(0.f, 0.f, 0.f, 0.f);
#pragma unroll
    for (int dx = 0; dx < 9; ++dx) *(float4*)(obase + (size_t)dx * PLANE) = z;
    return;
  }

  u32* S = &lds[dy][0];                     // 4 slots x [4 pad | 256 | 4 pad]
  if (lane < DEPTH * 8) {                   // zero side-pads once (wave-private)
    const int slot = lane >> 3, pd = lane & 7;
    S[slot * 264 + (pd < 4 ? pd : 256 + pd)] = 0;
  }

  const u32* sg = ps + (size_t)(b * NCP) * PLANE + (size_t)gh * WW + l4;
  const u32* fg = pf + (size_t)(b * NCP) * PLANE + (size_t)h  * WW + l4;

  u32x4 fr[DEPTH];                          // packed-F ring, compile-time indices

  auto pair = [&](int cp) {                 // 2 vmem, order: S-gload, F
    const int slot = cp % DEPTH;
    gload_lds16(sg + (size_t)cp * PLANE, S + slot * 264 + 4);
    // All 9 dy-waves load the IDENTICAL F address -> L1/MSHR merge.
    fr[slot] = *(const u32x4*)(fg + (size_t)cp * PLANE);
  };

#pragma unroll
  for (int cp = 0; cp < AHEAD; ++cp) pair(cp);    // 3 pairs = 6 vmem in flight

  float acc[36];
#pragma unroll
  for (int k = 0; k < 36; ++k) acc[k] = 0.f;

#pragma unroll
  for (int cp = 0; cp < NCP; ++cp) {
    const int rem = NCP - 1 - cp;
    waitA(rem);                             // S-gload of cp landed in LDS
    __builtin_amdgcn_sched_barrier(0);      // rule 18: no ds_read above the wait
    const int slot = cp % DEPTH;
    const u32x4 s0 = *(const u32x4*)(S + slot * 264 + l4);       // w-4..w-1
    const u32x4 s1 = *(const u32x4*)(S + slot * 264 + l4 + 4);   // w..w+3
    const u32x4 s2 = *(const u32x4*)(S + slot * 264 + l4 + 8);   // w+4..w+7
    if (cp + AHEAD < NCP) pair(cp + AHEAD); // slot (cp-1)%4 consumed at cp-1

    waitB(rem);                             // F of cp in regs; later pairs fly on
    __builtin_amdgcn_sched_barrier(0);
    U32H2 f_[4], s_[12];
#pragma unroll
    for (int i = 0; i < 4; ++i) f_[i].u = fr[slot][i];
#pragma unroll
    for (int j = 0; j < 4; ++j) { s_[j].u = s0[j]; s_[j + 4].u = s1[j]; s_[j + 8].u = s2[j]; }
#pragma unroll
    for (int dx = 0; dx < 9; ++dx)
#pragma unroll
      for (int i = 0; i < 4; ++i)
        acc[dx * 4 + i] = __builtin_amdgcn_fdot2(f_[i].h, s_[i + dx].h,
                                                 acc[dx * 4 + i], false);
  }

  const float sc = 1.0f / 64.0f;
#pragma unroll
  for (int dx = 0; dx < 9; ++dx) {
    float4 v = make_float4(acc[dx * 4 + 0] * sc, acc[dx * 4 + 1] * sc,
                           acc[dx * 4 + 2] * sc, acc[dx * 4 + 3] * sc);
    *(float4*)(obase + (size_t)dx * PLANE) = v;
  }
}

// ---- fallback (proven-correct fp32 path) if ws is too small ----
__global__ __launch_bounds__(576) void corr_fp32_fb(
    const float* __restrict__ first, const float* __restrict__ second,
    float* __restrict__ out)
{
  const int tid  = threadIdx.x;
  const int lane = tid & 63;
  const int wv   = tid >> 6;
  const int bid  = blockIdx.x;
  const int idx  = bid >> 3;
  const int h    = (bid & 7) * 16 + (idx & 15);
  const int b    = idx >> 4;
  const int l4   = lane * 4;
  const size_t plane = (size_t)HH * WW;
  float* obase = out + (((size_t)b * 81 + (size_t)wv * 9) * HH + h) * WW + l4;
  const int gh = h + wv - 4;
  if (gh < 0 || gh >= HH) {
    const float4 z = make_float4(0.f, 0.f, 0.f, 0.f);
#pragma unroll
    for (int dx = 0; dx < 9; ++dx) *(float4*)(obase + (size_t)dx * plane) = z;
    return;
  }
  const float* frow = first  + ((size_t)b * 64 * HH + h ) * WW;
  const float* srow = second + ((size_t)b * 64 * HH + gh) * WW;
  const bool zL = (lane == 0), zR = (lane == 63);
  const int offL = zL ? l4 : l4 - 4;
  const int offR = zR ? l4 : l4 + 4;
  float acc[9][4];
#pragma unroll
  for (int dx = 0; dx < 9; ++dx)
#pragma unroll
    for (int i = 0; i < 4; ++i) acc[dx][i] = 0.f;
#pragma unroll 2
  for (int c = 0; c < 64; ++c) {
    const size_t cp = (size_t)c * plane;
    float4 f  = *(const float4*)(frow + cp + l4);
    float4 aL = *(const float4*)(srow + cp + offL);
    float4 aM = *(const float4*)(srow + cp + l4);
    float4 aR = *(const float4*)(srow + cp + offR);
    if (zL) { aL.x = aL.y = aL.z = aL.w = 0.f; }
    if (zR) { aR.x = aR.y = aR.z = aR.w = 0.f; }
    const float fv[4]  = {f.x, f.y, f.z, f.w};
    const float sv[12] = {aL.x, aL.y, aL.z, aL.w, aM.x, aM.y, aM.z, aM.w,
                          aR.x, aR.y, aR.z, aR.w};
#pragma unroll
    for (int dx = 0; dx < 9; ++dx)
#pragma unroll
      for (int i = 0; i < 4; ++i)
        acc[dx][i] = fmaf(fv[i], sv[i + dx], acc[dx][i]);
  }
  const float sc = 1.0f / 64.0f;
#pragma unroll
  for (int dx = 0; dx < 9; ++dx) {
    float4 v = make_float4(acc[dx][0] * sc, acc[dx][1] * sc,
                           acc[dx][2] * sc, acc[dx][3] * sc);
    *(float4*)(obase + (size_t)dx * plane) = v;
  }
}

extern "C" void kernel_launch(void* const* d_in, const int* in_sizes, int n_in,
                              void* d_out, int out_size, void* d_ws, size_t ws_size,
                              hipStream_t stream) {
  const float* first  = (const float*)d_in[0];
  const float* second = (const float*)d_in[1];
  float* out = (float*)d_out;
  (void)in_sizes; (void)n_in; (void)out_size;

  if (ws_size >= 2ull * PACKED_DWORDS * 4ull) {
    u32* pfirst  = (u32*)d_ws;
    u32* psecond = pfirst + PACKED_DWORDS;
    pack_kernel<<<dim3(8192), dim3(256), 0, stream>>>(first, second, pfirst, psecond);
    corr_f16  <<<dim3(512),  dim3(576), 0, stream>>>(psecond, pfirst, out);
  } else {
    corr_fp32_fb<<<dim3(512), dim3(576), 0, stream>>>(first, second, out);
  }
}

// Round 21
// 37.878 us; speedup vs baseline: 10.0563x; 1.0771x over previous
//
#include <hip/hip_runtime.h>

#define HH 128
#define WW 256
#define DEPTH 4          // LDS/F ring slots per wave
#define AHEAD 3          // channel-pairs in flight; 3 vmem per pair
#define NCP 32           // 64 channels -> 32 channel-pairs
#define PLANE 32768      // H*W dwords per plane
#define PACKED_DWORDS 4194304ull   // packed S: 4 b * 32 cp * 32768

typedef unsigned int u32;
typedef _Float16 f16;
typedef f16 f16x2 __attribute__((ext_vector_type(2)));
typedef u32 u32x4 __attribute__((ext_vector_type(4)));

union U32H2 { u32 u; f16x2 h; };

// async global->LDS, 16B/lane: global src per-lane, LDS dest uniform base + lane*16.
__device__ __forceinline__ void gload_lds16(const u32* g, u32* l) {
  __builtin_amdgcn_global_load_lds(
      (const __attribute__((address_space(1))) u32*)g,
      (__attribute__((address_space(3))) u32*)l, 16, 0, 0);
}

// Stage A: drain only the S-gload (oldest op) of pair cp.
__device__ __forceinline__ void waitA(int rem) {   // compile-time after unroll
  if      (rem >= 2) asm volatile("s_waitcnt vmcnt(8)" ::: "memory");
  else if (rem == 1) asm volatile("s_waitcnt vmcnt(5)" ::: "memory");
  else               asm volatile("s_waitcnt vmcnt(2)" ::: "memory");
}
// Stage B: drain pair cp's two F loads (next-oldest), after pair(cp+3) issue.
__device__ __forceinline__ void waitB(int rem) {
  if      (rem >= 3) asm volatile("s_waitcnt vmcnt(9)" ::: "memory");
  else if (rem == 2) asm volatile("s_waitcnt vmcnt(6)" ::: "memory");
  else if (rem == 1) asm volatile("s_waitcnt vmcnt(3)" ::: "memory");
  else               asm volatile("s_waitcnt vmcnt(0)" ::: "memory");
}

// ---- pack S only: fp32 [b][c][h][w] -> dword=half2(c,c+1) at [b][c/2][h][w] ----
__global__ __launch_bounds__(256) void pack_s(
    const float* __restrict__ src, u32* __restrict__ dst)
{
  const int di  = blockIdx.x * 1024 + threadIdx.x * 4;
  const int p   = di & (PLANE - 1);
  const int cpb = di >> 15;
  const int bI  = cpb >> 5, cp = cpb & 31;
  const size_t s0 = ((size_t)(bI * 64 + cp * 2)) * PLANE + p;
  const float4 x = *(const float4*)(src + s0);
  const float4 y = *(const float4*)(src + s0 + PLANE);
  U32H2 h0, h1, h2, h3;
  h0.h = f16x2{(f16)x.x, (f16)y.x};
  h1.h = f16x2{(f16)x.y, (f16)y.y};
  h2.h = f16x2{(f16)x.z, (f16)y.z};
  h3.h = f16x2{(f16)x.w, (f16)y.w};
  *(u32x4*)(dst + di) = (u32x4){h0.u, h1.u, h2.u, h3.u};
}

// ---- correlation: block=(b,h), 9 dy-waves (champion structure).
// Two-stage vmcnt: ds_reads overlap the F-load tail instead of waiting on it.
__global__ __launch_bounds__(576, 5) void corr_f16(
    const u32* __restrict__ ps, const float* __restrict__ first,
    float* __restrict__ out)
{
  __shared__ u32 lds[9][DEPTH * 264];              // 38016 B/block

  const int tid  = threadIdx.x;
  const int lane = tid & 63;
  const int dy   = __builtin_amdgcn_readfirstlane(tid >> 6);  // 0..8, wave-uniform
  const int bid  = blockIdx.x;
  const int xcd  = bid & 7;                 // contiguous 16-row h band per XCD
  const int idx  = bid >> 3;                // 0..63
  const int h    = xcd * 16 + (idx & 15);
  const int b    = idx >> 4;                // 0..3
  const int l4   = lane * 4;

  float* obase = out + (((size_t)(b * 81 + dy * 9)) * HH + h) * WW + l4;
  const int gh = h + dy - 4;
  if (gh < 0 || gh >= HH) {                 // whole row OOB -> zeros, exit
    const float4 z = make_float4(0.f, 0.f, 0.f, 0.f);
#pragma unroll
    for (int dx = 0; dx < 9; ++dx) *(float4*)(obase + (size_t)dx * PLANE) = z;
    return;
  }

  u32* S = &lds[dy][0];                     // 4 slots x [4 pad | 256 | 4 pad]
  if (lane < DEPTH * 8) {                   // zero side-pads once (wave-private)
    const int slot = lane >> 3, pd = lane & 7;
    S[slot * 264 + (pd < 4 ? pd : 256 + pd)] = 0;
  }

  const u32*   sg = ps    + (size_t)(b * NCP) * PLANE + (size_t)gh * WW + l4;
  const float* fg = first + (size_t)(b * 64) * PLANE + (size_t)h * WW + l4;

  float4 frx[DEPTH], fry[DEPTH];            // F ring (fp32), compile-time indices

  auto pair = [&](int cp) {                 // 3 vmem, order: S-gload, F c, F c+1
    const int slot = cp % DEPTH;
    gload_lds16(sg + (size_t)cp * PLANE, S + slot * 264 + 4);
    frx[slot] = *(const float4*)(fg + (size_t)(2 * cp) * PLANE);
    fry[slot] = *(const float4*)(fg + (size_t)(2 * cp + 1) * PLANE);
  };

#pragma unroll
  for (int cp = 0; cp < AHEAD; ++cp) pair(cp);    // 3 pairs = 9 vmem in flight

  float acc[36];
#pragma unroll
  for (int k = 0; k < 36; ++k) acc[k] = 0.f;

#pragma unroll
  for (int cp = 0; cp < NCP; ++cp) {
    const int rem = NCP - 1 - cp;
    waitA(rem);                             // S-gload of cp landed in LDS
    __builtin_amdgcn_sched_barrier(0);      // rule 18: no ds_read above the wait
    const int slot = cp % DEPTH;
    const u32x4 s0 = *(const u32x4*)(S + slot * 264 + l4);       // w-4..w-1
    const u32x4 s1 = *(const u32x4*)(S + slot * 264 + l4 + 4);   // w..w+3
    const u32x4 s2 = *(const u32x4*)(S + slot * 264 + l4 + 8);   // w+4..w+7
    if (cp + AHEAD < NCP) pair(cp + AHEAD); // slot (cp-1)%4 was consumed at cp-1

    waitB(rem);                             // F of cp in regs; later pairs fly on
    __builtin_amdgcn_sched_barrier(0);
    U32H2 f_[4];                            // RNE fp32->f16 pack (matches pack_s)
    f_[0].h = f16x2{(f16)frx[slot].x, (f16)fry[slot].x};
    f_[1].h = f16x2{(f16)frx[slot].y, (f16)fry[slot].y};
    f_[2].h = f16x2{(f16)frx[slot].z, (f16)fry[slot].z};
    f_[3].h = f16x2{(f16)frx[slot].w, (f16)fry[slot].w};

    U32H2 s_[12];
#pragma unroll
    for (int j = 0; j < 4; ++j) { s_[j].u = s0[j]; s_[j + 4].u = s1[j]; s_[j + 8].u = s2[j]; }
#pragma unroll
    for (int dx = 0; dx < 9; ++dx)
#pragma unroll
      for (int i = 0; i < 4; ++i)
        acc[dx * 4 + i] = __builtin_amdgcn_fdot2(f_[i].h, s_[i + dx].h,
                                                 acc[dx * 4 + i], false);
  }

  const float sc = 1.0f / 64.0f;
#pragma unroll
  for (int dx = 0; dx < 9; ++dx) {
    float4 v = make_float4(acc[dx * 4 + 0] * sc, acc[dx * 4 + 1] * sc,
                           acc[dx * 4 + 2] * sc, acc[dx * 4 + 3] * sc);
    *(float4*)(obase + (size_t)dx * PLANE) = v;
  }
}

// ---- fallback (proven-correct fp32 path) if ws is too small ----
__global__ __launch_bounds__(576) void corr_fp32_fb(
    const float* __restrict__ first, const float* __restrict__ second,
    float* __restrict__ out)
{
  const int tid  = threadIdx.x;
  const int lane = tid & 63;
  const int wv   = tid >> 6;
  const int bid  = blockIdx.x;
  const int idx  = bid >> 3;
  const int h    = (bid & 7) * 16 + (idx & 15);
  const int b    = idx >> 4;
  const int l4   = lane * 4;
  const size_t plane = (size_t)HH * WW;
  float* obase = out + (((size_t)b * 81 + (size_t)wv * 9) * HH + h) * WW + l4;
  const int gh = h + wv - 4;
  if (gh < 0 || gh >= HH) {
    const float4 z = make_float4(0.f, 0.f, 0.f, 0.f);
#pragma unroll
    for (int dx = 0; dx < 9; ++dx) *(float4*)(obase + (size_t)dx * plane) = z;
    return;
  }
  const float* frow = first  + ((size_t)b * 64 * HH + h ) * WW;
  const float* srow = second + ((size_t)b * 64 * HH + gh) * WW;
  const bool zL = (lane == 0), zR = (lane == 63);
  const int offL = zL ? l4 : l4 - 4;
  const int offR = zR ? l4 : l4 + 4;
  float acc[9][4];
#pragma unroll
  for (int dx = 0; dx < 9; ++dx)
#pragma unroll
    for (int i = 0; i < 4; ++i) acc[dx][i] = 0.f;
#pragma unroll 2
  for (int c = 0; c < 64; ++c) {
    const size_t cp = (size_t)c * plane;
    float4 f  = *(const float4*)(frow + cp + l4);
    float4 aL = *(const float4*)(srow + cp + offL);
    float4 aM = *(const float4*)(srow + cp + l4);
    float4 aR = *(const float4*)(srow + cp + offR);
    if (zL) { aL.x = aL.y = aL.z = aL.w = 0.f; }
    if (zR) { aR.x = aR.y = aR.z = aR.w = 0.f; }
    const float fv[4]  = {f.x, f.y, f.z, f.w};
    const float sv[12] = {aL.x, aL.y, aL.z, aL.w, aM.x, aM.y, aM.z, aM.w,
                          aR.x, aR.y, aR.z, aR.w};
#pragma unroll
    for (int dx = 0; dx < 9; ++dx)
#pragma unroll
      for (int i = 0; i < 4; ++i)
        acc[dx][i] = fmaf(fv[i], sv[i + dx], acc[dx][i]);
  }
  const float sc = 1.0f / 64.0f;
#pragma unroll
  for (int dx = 0; dx < 9; ++dx) {
    float4 v = make_float4(acc[dx][0] * sc, acc[dx][1] * sc,
                           acc[dx][2] * sc, acc[dx][3] * sc);
    *(float4*)(obase + (size_t)dx * plane) = v;
  }
}

extern "C" void kernel_launch(void* const* d_in, const int* in_sizes, int n_in,
                              void* d_out, int out_size, void* d_ws, size_t ws_size,
                              hipStream_t stream) {
  const float* first  = (const float*)d_in[0];
  const float* second = (const float*)d_in[1];
  float* out = (float*)d_out;
  (void)in_sizes; (void)n_in; (void)out_size;

  if (ws_size >= PACKED_DWORDS * 4ull) {
    u32* psecond = (u32*)d_ws;
    pack_s  <<<dim3(4096), dim3(256), 0, stream>>>(second, psecond);
    corr_f16<<<dim3(512),  dim3(576), 0, stream>>>(psecond, first, out);
  } else {
    corr_fp32_fb<<<dim3(512), dim3(576), 0, stream>>>(first, second, out);
  }
}